// Round 2
// baseline (2605.380 us; speedup 1.0000x reference)
//
#include <hip/hip_runtime.h>
#include <hip/hip_fp16.h>

#define TSEQ  2048
#define BATCH 64
#define DIN   128
#define DH    256
#define WSTR  384   // W row stride = dimIn + dimH

typedef __fp16 h2 __attribute__((ext_vector_type(2)));

#if defined(__has_builtin)
#if __has_builtin(__builtin_amdgcn_fdot2)
#define HAVE_FDOT2 1
#endif
#endif

static __device__ __forceinline__ h2 bc_h2(unsigned int u) {
    return __builtin_bit_cast(h2, u);
}

// LDS-only workgroup barrier: drains lgkmcnt (LDS) but NOT vmcnt, so global
// loads/stores stay in flight across steps. __syncthreads() would emit
// s_waitcnt vmcnt(0) lgkmcnt(0) and serialize the xw prefetch into every step.
#define LDS_BARRIER() asm volatile("s_waitcnt lgkmcnt(0)\n\ts_barrier" ::: "memory")

// ---------------- Phase 1: xw = x @ Wx^T + b, written into d_out ----------------
// grid: (BT/32, 256/64), block: 256 threads. Tile 32 rows x 64 cols, K=128.
__global__ __launch_bounds__(256) void xw_gemm(const float* __restrict__ x,
                                               const float* __restrict__ W,
                                               const float* __restrict__ bias,
                                               float* __restrict__ out) {
    __shared__ float xs[32][132];
    __shared__ float ws[64][129];

    const int tid = threadIdx.x;
    const int R0 = blockIdx.x * 32;
    const int C0 = blockIdx.y * 64;

    {
        const float4* x4 = (const float4*)x;
        int idx = tid;
#pragma unroll
        for (int q = 0; q < 4; ++q, idx += 256) {
            int r  = idx >> 5;
            int kq = idx & 31;
            float4 f = x4[(size_t)(R0 + r) * 32 + kq];
            *(float4*)&xs[r][kq * 4] = f;
        }
    }
    {
        const float4* W4 = (const float4*)W;   // row stride 96 float4
        int idx = tid;
#pragma unroll
        for (int q = 0; q < 8; ++q, idx += 256) {
            int c  = idx >> 5;
            int kq = idx & 31;
            float4 f = W4[(size_t)(C0 + c) * 96 + kq];
            ws[c][kq * 4 + 0] = f.x;
            ws[c][kq * 4 + 1] = f.y;
            ws[c][kq * 4 + 2] = f.z;
            ws[c][kq * 4 + 3] = f.w;
        }
    }
    __syncthreads();

    const int cx = (tid & 15) * 4;
    const int r2 = tid >> 4;
    float a00 = 0.f, a01 = 0.f, a02 = 0.f, a03 = 0.f;
    float a10 = 0.f, a11 = 0.f, a12 = 0.f, a13 = 0.f;

#pragma unroll 4
    for (int k = 0; k < 128; ++k) {
        float xa = xs[r2][k];
        float xb = xs[r2 + 16][k];
        float w0 = ws[cx + 0][k];
        float w1 = ws[cx + 1][k];
        float w2 = ws[cx + 2][k];
        float w3 = ws[cx + 3][k];
        a00 = fmaf(xa, w0, a00); a01 = fmaf(xa, w1, a01);
        a02 = fmaf(xa, w2, a02); a03 = fmaf(xa, w3, a03);
        a10 = fmaf(xb, w0, a10); a11 = fmaf(xb, w1, a11);
        a12 = fmaf(xb, w2, a12); a13 = fmaf(xb, w3, a13);
    }

    float4 bi = *(const float4*)&bias[C0 + cx];
    float4 o0 = {a00 + bi.x, a01 + bi.y, a02 + bi.z, a03 + bi.w};
    float4 o1 = {a10 + bi.x, a11 + bi.y, a12 + bi.z, a13 + bi.w};
    *(float4*)&out[(size_t)(R0 + r2) * DH + C0 + cx] = o0;
    *(float4*)&out[(size_t)(R0 + r2 + 16) * DH + C0 + cx] = o1;
}

// ---------------- Phase 2: sequential scan, one block per batch ----------------
// Thread j owns hidden unit j; Wh row j register-resident as 128 fp16 pairs.
// h double-buffered in LDS (fp16). Inner loop uses an lgkm-only barrier so the
// rolling depth-8 xw prefetch and the h store never drain inside a step.
__global__ __launch_bounds__(256, 1) void rnn_scan(const float* __restrict__ W,
                                                   const float* __restrict__ h0,
                                                   float* __restrict__ out) {
    __shared__ __align__(16) __fp16 hbuf[2][DH];

    const int j = threadIdx.x;
    const int b = blockIdx.x;

    // Wh row j -> 128 packed fp16 pairs (register-resident)
    h2 w[DH / 2];
    {
        const float4* Wr = (const float4*)(W + (size_t)j * WSTR + DIN);
#pragma unroll
        for (int q = 0; q < 64; ++q) {
            float4 f = Wr[q];
            w[2 * q]     = h2{(__fp16)f.x, (__fp16)f.y};
            w[2 * q + 1] = h2{(__fp16)f.z, (__fp16)f.w};
        }
    }

    hbuf[0][j] = (__fp16)h0[(size_t)b * DH + j];

    float* orow = out + (size_t)b * TSEQ * DH + j;

    // depth-8 rolling prefetch of xw (phase 1 wrote it into out)
    float xwb[8];
#pragma unroll
    for (int i = 0; i < 8; ++i) xwb[i] = orow[(size_t)i * DH];

    LDS_BARRIER();

    int p = 0;
    for (int t0 = 0; t0 < TSEQ; t0 += 8) {
#pragma unroll
        for (int u = 0; u < 8; ++u) {
            const int t = t0 + u;
            float xw = xwb[u];
            if (t + 8 < TSEQ) xwb[u] = orow[(size_t)(t + 8) * DH];  // lands ~8 steps from now

            const uint4* hp = (const uint4*)hbuf[p];
            float a0 = 0.f, a1 = 0.f, a2 = 0.f, a3 = 0.f;
            float a4 = 0.f, a5 = 0.f, a6 = 0.f, a7 = 0.f;

#ifdef HAVE_FDOT2
#pragma unroll
            for (int c = 0; c < 16; ++c) {
                uint4 v0 = hp[2 * c];       // broadcast ds_read_b128 (all lanes same addr)
                uint4 v1 = hp[2 * c + 1];
                a0 = __builtin_amdgcn_fdot2(w[8 * c + 0], bc_h2(v0.x), a0, false);
                a1 = __builtin_amdgcn_fdot2(w[8 * c + 1], bc_h2(v0.y), a1, false);
                a2 = __builtin_amdgcn_fdot2(w[8 * c + 2], bc_h2(v0.z), a2, false);
                a3 = __builtin_amdgcn_fdot2(w[8 * c + 3], bc_h2(v0.w), a3, false);
                a4 = __builtin_amdgcn_fdot2(w[8 * c + 4], bc_h2(v1.x), a4, false);
                a5 = __builtin_amdgcn_fdot2(w[8 * c + 5], bc_h2(v1.y), a5, false);
                a6 = __builtin_amdgcn_fdot2(w[8 * c + 6], bc_h2(v1.z), a6, false);
                a7 = __builtin_amdgcn_fdot2(w[8 * c + 7], bc_h2(v1.w), a7, false);
            }
#else
#pragma unroll
            for (int c = 0; c < 32; ++c) {
                uint4 v = hp[c];
                h2 hh0 = bc_h2(v.x), hh1 = bc_h2(v.y), hh2 = bc_h2(v.z), hh3 = bc_h2(v.w);
                h2 w0 = w[4 * c + 0], w1 = w[4 * c + 1], w2 = w[4 * c + 2], w3 = w[4 * c + 3];
                a0 = fmaf((float)w0.x, (float)hh0.x, a0);
                a1 = fmaf((float)w0.y, (float)hh0.y, a1);
                a2 = fmaf((float)w1.x, (float)hh1.x, a2);
                a3 = fmaf((float)w1.y, (float)hh1.y, a3);
                a4 = fmaf((float)w2.x, (float)hh2.x, a4);
                a5 = fmaf((float)w2.y, (float)hh2.y, a5);
                a6 = fmaf((float)w3.x, (float)hh3.x, a6);
                a7 = fmaf((float)w3.y, (float)hh3.y, a7);
            }
#endif
            float pre = xw + (((a0 + a1) + (a2 + a3)) + ((a4 + a5) + (a6 + a7)));
            // tanh(x) = 1 - 2/(e^(2x)+1)
            float e  = __expf(2.0f * pre);
            float hn = 1.0f - 2.0f * __builtin_amdgcn_rcpf(e + 1.0f);

            hbuf[p ^ 1][j] = (__fp16)hn;
            LDS_BARRIER();
            orow[(size_t)t * DH] = hn;   // fire-and-forget; never drained in-loop

            p ^= 1;
        }
    }
}

extern "C" void kernel_launch(void* const* d_in, const int* in_sizes, int n_in,
                              void* d_out, int out_size, void* d_ws, size_t ws_size,
                              hipStream_t stream) {
    const float* x    = (const float*)d_in[0];
    const float* h0   = (const float*)d_in[1];
    const float* W    = (const float*)d_in[2];
    const float* bias = (const float*)d_in[3];
    float* out = (float*)d_out;

    dim3 g1(BATCH * TSEQ / 32, DH / 64);
    xw_gemm<<<g1, 256, 0, stream>>>(x, W, bias, out);
    rnn_scan<<<BATCH, 256, 0, stream>>>(W, h0, out);
}

// Round 3
// 1684.716 us; speedup vs baseline: 1.5465x; 1.5465x over previous
//
#include <hip/hip_runtime.h>
#include <hip/hip_fp16.h>

#define TSEQ  2048
#define BATCH 64
#define DIN   128
#define DH    256
#define WSTR  384   // W row stride = dimIn + dimH

typedef __fp16 h2    __attribute__((ext_vector_type(2)));
typedef __fp16 f16x8 __attribute__((ext_vector_type(8)));
typedef float  f32x4 __attribute__((ext_vector_type(4)));

static __device__ __forceinline__ h2 bc_h2(unsigned int u) {
    return __builtin_bit_cast(h2, u);
}
// butterfly exchange within 32-lane groups (q = lane&3, so partners stay in-group)
static __device__ __forceinline__ float swz_xor1(float v) {
    return __builtin_bit_cast(float,
        __builtin_amdgcn_ds_swizzle(__builtin_bit_cast(int, v), 0x041F));
}
static __device__ __forceinline__ float swz_xor2(float v) {
    return __builtin_bit_cast(float,
        __builtin_amdgcn_ds_swizzle(__builtin_bit_cast(int, v), 0x081F));
}

// ---------------- Phase 1: xw = x @ Wx^T + b (f16 MFMA), into d_out ----------
// grid: BT/64 blocks, 256 thr (4 waves). Tile M=64, N=256 (wave = 64-col strip),
// K=128 one-shot. A (x) staged fp32->f16 in LDS; B (Wx) frags loaded from
// L2-hot W directly into registers.
__global__ __launch_bounds__(256) void xw_gemm(const float* __restrict__ x,
                                               const float* __restrict__ W,
                                               const float* __restrict__ bias,
                                               float* __restrict__ out) {
    __shared__ __align__(16) __fp16 af[64][136];   // pad 128->136: lane m vs m+8 only 2-way (free)

    const int tid  = threadIdx.x;
    const int lane = tid & 63;
    const int wv   = tid >> 6;            // wave id -> N strip [64*wv, 64*wv+64)
    const int row0 = blockIdx.x * 64;     // flat (b*T+t) row base
    const int nlo  = lane & 15;
    const int quad = lane >> 4;

    // stage A: 64 rows x 128 k, fp32 -> f16
    {
        const int r  = tid >> 2;
        const int c0 = (tid & 3) * 32;
        const float4* xr = (const float4*)(x + (size_t)(row0 + r) * DIN) + (tid & 3) * 8;
#pragma unroll
        for (int i = 0; i < 4; ++i) {
            float4 f0 = xr[2 * i];
            float4 f1 = xr[2 * i + 1];
            f16x8 v;
            v[0]=(__fp16)f0.x; v[1]=(__fp16)f0.y; v[2]=(__fp16)f0.z; v[3]=(__fp16)f0.w;
            v[4]=(__fp16)f1.x; v[5]=(__fp16)f1.y; v[6]=(__fp16)f1.z; v[7]=(__fp16)f1.w;
            *(f16x8*)&af[r][c0 + i * 8] = v;
        }
    }

    // B frags: lane&15 = n, k = kk*32 + quad*8 + j
    f16x8 bfr[4][4];   // [n0][kk]
#pragma unroll
    for (int n0 = 0; n0 < 4; ++n0) {
        const int n = wv * 64 + n0 * 16 + nlo;
        const float* wr = W + (size_t)n * WSTR;
#pragma unroll
        for (int kk = 0; kk < 4; ++kk) {
            const int k = kk * 32 + quad * 8;
            float4 f0 = *(const float4*)(wr + k);
            float4 f1 = *(const float4*)(wr + k + 4);
            f16x8 v;
            v[0]=(__fp16)f0.x; v[1]=(__fp16)f0.y; v[2]=(__fp16)f0.z; v[3]=(__fp16)f0.w;
            v[4]=(__fp16)f1.x; v[5]=(__fp16)f1.y; v[6]=(__fp16)f1.z; v[7]=(__fp16)f1.w;
            bfr[n0][kk] = v;
        }
    }
    __syncthreads();

    f32x4 acc[4][4];   // [m0][n0]
#pragma unroll
    for (int m0 = 0; m0 < 4; ++m0)
#pragma unroll
        for (int n0 = 0; n0 < 4; ++n0) acc[m0][n0] = (f32x4)0.0f;

#pragma unroll
    for (int kk = 0; kk < 4; ++kk) {
#pragma unroll
        for (int m0 = 0; m0 < 4; ++m0) {
            f16x8 a = *(const f16x8*)&af[m0 * 16 + nlo][kk * 32 + quad * 8];
#pragma unroll
            for (int n0 = 0; n0 < 4; ++n0)
                acc[m0][n0] = __builtin_amdgcn_mfma_f32_16x16x32_f16(
                                  a, bfr[n0][kk], acc[m0][n0], 0, 0, 0);
        }
    }

    // epilogue: +bias, store. C/D: col = lane&15, row = quad*4 + r
#pragma unroll
    for (int n0 = 0; n0 < 4; ++n0) {
        const int col = wv * 64 + n0 * 16 + nlo;
        const float bn = bias[col];
#pragma unroll
        for (int m0 = 0; m0 < 4; ++m0)
#pragma unroll
            for (int r = 0; r < 4; ++r) {
                const int row = row0 + m0 * 16 + quad * 4 + r;
                out[(size_t)row * DH + col] = acc[m0][n0][r] + bn;
            }
    }
}

// ---------------- Phase 2: sequential scan, one block per batch ----------------
// thread (g = tid>>2, q = tid&3): partial dots of outputs 4g..4g+3 over h
// segment [64q, 64q+64); 3-swizzle butterfly over q -> thread tid owns output
// tid. All VMEM chunked per 16 steps (xw chunk in LDS, h ring in LDS) so the
// per-step __syncthreads has nothing in vmcnt to drain.
__global__ __launch_bounds__(256, 1) void rnn_scan(const float* __restrict__ W,
                                                   const float* __restrict__ h0,
                                                   float* __restrict__ out) {
    __shared__ __align__(16) __fp16 hseg[2][4][72];   // 4 segs of 64, pad +8: conflict-free
    __shared__ __align__(16) float  ring[16 * DH];    // 16 steps of h (fp32) awaiting dump
    __shared__ float                xwb[16 * DH];     // current chunk's xw

    const int tid = threadIdx.x;
    const int b   = blockIdx.x;
    const int q   = tid & 3;
    const int g   = tid >> 2;
    const bool b0 = (q & 1) != 0;
    const bool b1 = (q >> 1) != 0;

    // Wh f16: rows 4g..4g+3, k in [64q, 64q+64)  -> 128 VGPRs
    h2 w[4][32];
#pragma unroll
    for (int o = 0; o < 4; ++o) {
        const float* wr = W + (size_t)(4 * g + o) * WSTR + DIN + 64 * q;
#pragma unroll
        for (int i = 0; i < 16; ++i) {
            float4 f = *(const float4*)(wr + 4 * i);
            w[o][2 * i]     = h2{(__fp16)f.x, (__fp16)f.y};
            w[o][2 * i + 1] = h2{(__fp16)f.z, (__fp16)f.w};
        }
    }

    hseg[0][tid >> 6][tid & 63] = (__fp16)h0[(size_t)b * DH + tid];

    const float* orow = out + (size_t)b * TSEQ * DH + tid;   // xw column tid
    float* obase = out + (size_t)b * TSEQ * DH;

    // prologue: xw chunk 0 -> LDS
#pragma unroll
    for (int s = 0; s < 16; ++s) xwb[s * DH + tid] = orow[(size_t)s * DH];

    __syncthreads();

    int p = 0;
    for (int t0 = 0; t0 < TSEQ; t0 += 16) {
        for (int s = 0; s < 16; ++s) {
            const uint4* hp = (const uint4*)&hseg[p][q][0];
            float P0 = 0.f, P1 = 0.f, P2 = 0.f, P3 = 0.f;
#pragma unroll
            for (int i = 0; i < 8; ++i) {
                uint4 v = hp[i];
                h2 ha = bc_h2(v.x), hb = bc_h2(v.y), hc = bc_h2(v.z), hd = bc_h2(v.w);
                P0 = __builtin_amdgcn_fdot2(w[0][4*i], ha, P0, false);
                P1 = __builtin_amdgcn_fdot2(w[1][4*i], ha, P1, false);
                P2 = __builtin_amdgcn_fdot2(w[2][4*i], ha, P2, false);
                P3 = __builtin_amdgcn_fdot2(w[3][4*i], ha, P3, false);
                P0 = __builtin_amdgcn_fdot2(w[0][4*i+1], hb, P0, false);
                P1 = __builtin_amdgcn_fdot2(w[1][4*i+1], hb, P1, false);
                P2 = __builtin_amdgcn_fdot2(w[2][4*i+1], hb, P2, false);
                P3 = __builtin_amdgcn_fdot2(w[3][4*i+1], hb, P3, false);
                P0 = __builtin_amdgcn_fdot2(w[0][4*i+2], hc, P0, false);
                P1 = __builtin_amdgcn_fdot2(w[1][4*i+2], hc, P1, false);
                P2 = __builtin_amdgcn_fdot2(w[2][4*i+2], hc, P2, false);
                P3 = __builtin_amdgcn_fdot2(w[3][4*i+2], hc, P3, false);
                P0 = __builtin_amdgcn_fdot2(w[0][4*i+3], hd, P0, false);
                P1 = __builtin_amdgcn_fdot2(w[1][4*i+3], hd, P1, false);
                P2 = __builtin_amdgcn_fdot2(w[2][4*i+3], hd, P2, false);
                P3 = __builtin_amdgcn_fdot2(w[3][4*i+3], hd, P3, false);
            }

            // butterfly over q: round 1 (xor 1) keeps o with o&1==q&1
            float sendA = b0 ? P0 : P1;          // partner's needed P[!b0]
            float sendB = b0 ? P2 : P3;
            float keepA = b0 ? P1 : P0;          // my P[b0]
            float keepB = b0 ? P3 : P2;          // my P[b0+2]
            float S0 = keepA + swz_xor1(sendA);  // o = b0
            float S1 = keepB + swz_xor1(sendB);  // o = b0+2
            // round 2 (xor 2) keeps o == q
            float send2 = b1 ? S0 : S1;          // partner's needed S[!b1]
            float keep2 = b1 ? S1 : S0;          // my S[b1]
            float dot = keep2 + swz_xor2(send2);

            float pre = xwb[s * DH + tid] + dot;
            // tanh(x) = 1 - 2/(e^(2x)+1)
            float e  = __expf(2.0f * pre);
            float hn = 1.0f - 2.0f * __builtin_amdgcn_rcpf(e + 1.0f);

            ring[s * DH + tid] = hn;
            hseg[p ^ 1][tid >> 6][tid & 63] = (__fp16)hn;
            __syncthreads();                     // no VMEM in flight -> cheap
            p ^= 1;
        }

        // chunk boundary: dump ring -> out (coalesced float4), load next xw chunk
        {
            const float4* r4 = (const float4*)ring;
#pragma unroll
            for (int k = 0; k < 4; ++k) {
                const int e = tid + 256 * k;     // flat float4 index: s = e>>6, j = (e&63)*4
                float4 v = r4[e];
                *(float4*)&obase[(size_t)(t0 + (e >> 6)) * DH + (e & 63) * 4] = v;
            }
            if (t0 + 16 < TSEQ) {
#pragma unroll
                for (int s = 0; s < 16; ++s)
                    xwb[s * DH + tid] = orow[(size_t)(t0 + 16 + s) * DH];
            }
        }
        __syncthreads();   // one vmcnt drain per 16 steps (amortized ~50 cyc/step)
    }
}

extern "C" void kernel_launch(void* const* d_in, const int* in_sizes, int n_in,
                              void* d_out, int out_size, void* d_ws, size_t ws_size,
                              hipStream_t stream) {
    const float* x    = (const float*)d_in[0];
    const float* h0   = (const float*)d_in[1];
    const float* W    = (const float*)d_in[2];
    const float* bias = (const float*)d_in[3];
    float* out = (float*)d_out;

    xw_gemm<<<BATCH * TSEQ / 64, 256, 0, stream>>>(x, W, bias, out);
    rnn_scan<<<BATCH, 256, 0, stream>>>(W, h0, out);
}